// Round 7
// baseline (162.066 us; speedup 1.0000x reference)
//
#include <hip/hip_runtime.h>
#include <hip/hip_bf16.h>

// Chamfer loss: B=32, N=M=2048, D=3.
// loss[b] = 0.5 * ( sum_n ma[n]*min_m d2(a_n,b_m) + sum_m mb[m]*min_n d2(b_m,a_n) )
// masked pairs -> BIG^2 = 1e16 (exact in fp32: a2 < ulp(1e16)).
//
// R7: INSTRUMENTED ROUND. Real path = R5 structure (best so far, 85.3us).
// Added chamfer_diag: identical structure, tile loop run 4x with barriers
// (no CSE across passes), result kept live via a d_ws write. Purpose: main's
// true cost has been invisible (harness 40us fills own top-5) and invariant
// ~35us across R3-R6 with no identifiable pipe; diag forces main's counter
// row into top-5 and measures per-pass cost directly. R8 removes it.
#define B_    32
#define N_    2048
#define M_    2048
#define RW_   8        // rows per wave
#define GX_   32       // n-chunks per (b,dir): 2048 / (8 waves * 8 rows)
#define BIG2  1.0e16f
#define PASSES_ 4

typedef float v2f __attribute__((ext_vector_type(2)));

__device__ __forceinline__ v2f v2_fma(v2f a, v2f b, v2f c) {
#if __has_builtin(__builtin_elementwise_fma)
    return __builtin_elementwise_fma(a, b, c);
#else
    v2f r; r.x = fmaf(a.x, b.x, c.x); r.y = fmaf(a.y, b.y, c.y); return r;
#endif
}
__device__ __forceinline__ v2f v2_min(v2f a, v2f b) {
#if __has_builtin(__builtin_elementwise_min)
    return __builtin_elementwise_min(a, b);
#else
    v2f r; r.x = fminf(a.x, b.x); r.y = fminf(a.y, b.y); return r;
#endif
}
__device__ __forceinline__ v2f v2_splat(float s) { return (v2f){ s, s }; }

union F4V2 { float4 f4; struct { v2f lo, hi; } v; };

// ---------------- Real main (R5 structure, unchanged) ----------------
__global__ __launch_bounds__(512) void chamfer_main(
    const int* __restrict__ o_w, const float* __restrict__ o_pts,
    const int* __restrict__ t_w, const float* __restrict__ t_pts,
    float* __restrict__ partials)
{
    const int dir  = blockIdx.z;
    const int b    = blockIdx.y;
    const int tid  = threadIdx.x;
    const int lane = tid & 63;
    const int wv   = tid >> 6;
    const int row0 = blockIdx.x * (8 * RW_) + wv * RW_;

    const int*   wa; const float* pa;   // outer (row) side
    const int*   wb; const float* pb;   // inner (streamed) side
    if (dir == 0) { wa = o_w; pa = o_pts; wb = t_w; pb = t_pts; }
    else          { wa = t_w; pa = t_pts; wb = o_w; pb = o_pts; }

    __shared__ float4 sqA[M_ / 2];      // 16 KB
    __shared__ float4 sqB[M_ / 2];      // 16 KB
    __shared__ float  wsum[8];

    {
        const float2* src2 = (const float2*)(pb + (size_t)b * M_ * 3);
        const int2*   wb2  = (const int2*)(wb + (size_t)b * M_);
        #pragma unroll
        for (int k = 0; k < 2; ++k) {
            int p = tid + k * 512;
            float2 u0 = src2[p * 3 + 0];
            float2 u1 = src2[p * 3 + 1];
            float2 u2 = src2[p * 3 + 2];
            int2   mm = wb2[p];
            float x0 = u0.x, y0 = u0.y, z0 = u1.x;
            float x1 = u1.y, y1 = u2.x, z1 = u2.y;
            float n20 = fmaf(x0, x0, fmaf(y0, y0, z0 * z0));
            float n21 = fmaf(x1, x1, fmaf(y1, y1, z1 * z1));
            sqA[p] = make_float4(-2.f * x0, -2.f * x1, -2.f * y0, -2.f * y1);
            sqB[p] = make_float4(-2.f * z0, -2.f * z1,
                                 mm.x ? n20 : BIG2, mm.y ? n21 : BIG2);
        }
    }

    int base = __builtin_amdgcn_readfirstlane((b * N_ + row0) * 3);
    const float* rp = pa + base;
    float rx[RW_], ry[RW_], rz[RW_];
    #pragma unroll
    for (int r = 0; r < RW_; ++r) {
        rx[r] = rp[3 * r + 0];
        ry[r] = rp[3 * r + 1];
        rz[r] = rp[3 * r + 2];
    }
    __syncthreads();

    v2f acc[RW_];
    #pragma unroll
    for (int r = 0; r < RW_; ++r) acc[r] = v2_splat(3.4e38f);

    F4V2 qa, qb, na, nb;
    qa.f4 = sqA[lane];
    qb.f4 = sqB[lane];
    #pragma unroll 4
    for (int t = 0; t < M_ / 128; ++t) {
        if (t + 1 < M_ / 128) {
            na.f4 = sqA[(t + 1) * 64 + lane];
            nb.f4 = sqB[(t + 1) * 64 + lane];
        }
        v2f xs = qa.v.lo, ys = qa.v.hi, zs = qb.v.lo, ws = qb.v.hi;
        #pragma unroll
        for (int r = 0; r < RW_; ++r) {
            v2f d = v2_fma(v2_splat(rx[r]), xs,
                    v2_fma(v2_splat(ry[r]), ys,
                    v2_fma(v2_splat(rz[r]), zs, ws)));
            acc[r] = v2_min(acc[r], d);
        }
        qa = na; qb = nb;
    }

    int mbase = __builtin_amdgcn_readfirstlane(b * N_ + row0);
    const int* wp = wa + mbase;
    float sum = 0.0f;
    #pragma unroll
    for (int r = 0; r < RW_; ++r) {
        float m = fminf(acc[r].x, acc[r].y);
        #pragma unroll
        for (int off = 32; off; off >>= 1)
            m = fminf(m, __shfl_xor(m, off, 64));
        float a2 = fmaf(rx[r], rx[r], fmaf(ry[r], ry[r], rz[r] * rz[r]));
        float d2 = fmaxf(a2 + m, 0.0f);
        sum += (wp[r] != 0) ? d2 : 0.0f;
    }
    if (lane == 0) wsum[wv] = sum;
    __syncthreads();
    if (tid == 0) {
        float s = 0.f;
        #pragma unroll
        for (int i = 0; i < 8; ++i) s += wsum[i];
        partials[((size_t)b * 2 + dir) * GX_ + blockIdx.x] = s;
    }
}

// ---------------- Diagnostic clone: tile loop x PASSES_ ----------------
// Identical structure; per-pass results summed so no pass is dead code;
// __syncthreads() between passes blocks LDS-load CSE across passes.
__global__ __launch_bounds__(512) void chamfer_diag(
    const int* __restrict__ o_w, const float* __restrict__ o_pts,
    const int* __restrict__ t_w, const float* __restrict__ t_pts,
    float* __restrict__ diag_partials)
{
    const int dir  = blockIdx.z;
    const int b    = blockIdx.y;
    const int tid  = threadIdx.x;
    const int lane = tid & 63;
    const int wv   = tid >> 6;
    const int row0 = blockIdx.x * (8 * RW_) + wv * RW_;

    const float* pa;  const int* wb; const float* pb;
    if (dir == 0) { pa = o_pts; wb = t_w; pb = t_pts; }
    else          { pa = t_pts; wb = o_w; pb = o_pts; }

    __shared__ float4 sqA[M_ / 2];
    __shared__ float4 sqB[M_ / 2];
    __shared__ float  wsum[8];

    {
        const float2* src2 = (const float2*)(pb + (size_t)b * M_ * 3);
        const int2*   wb2  = (const int2*)(wb + (size_t)b * M_);
        #pragma unroll
        for (int k = 0; k < 2; ++k) {
            int p = tid + k * 512;
            float2 u0 = src2[p * 3 + 0];
            float2 u1 = src2[p * 3 + 1];
            float2 u2 = src2[p * 3 + 2];
            int2   mm = wb2[p];
            float x0 = u0.x, y0 = u0.y, z0 = u1.x;
            float x1 = u1.y, y1 = u2.x, z1 = u2.y;
            float n20 = fmaf(x0, x0, fmaf(y0, y0, z0 * z0));
            float n21 = fmaf(x1, x1, fmaf(y1, y1, z1 * z1));
            sqA[p] = make_float4(-2.f * x0, -2.f * x1, -2.f * y0, -2.f * y1);
            sqB[p] = make_float4(-2.f * z0, -2.f * z1,
                                 mm.x ? n20 : BIG2, mm.y ? n21 : BIG2);
        }
    }

    int base = __builtin_amdgcn_readfirstlane((b * N_ + row0) * 3);
    const float* rp = pa + base;
    float rx[RW_], ry[RW_], rz[RW_];
    #pragma unroll
    for (int r = 0; r < RW_; ++r) {
        rx[r] = rp[3 * r + 0];
        ry[r] = rp[3 * r + 1];
        rz[r] = rp[3 * r + 2];
    }
    __syncthreads();

    float total = 0.0f;
    #pragma unroll 1
    for (int pass = 0; pass < PASSES_; ++pass) {
        v2f acc[RW_];
        #pragma unroll
        for (int r = 0; r < RW_; ++r) acc[r] = v2_splat(3.4e38f);

        F4V2 qa, qb, na, nb;
        qa.f4 = sqA[lane];
        qb.f4 = sqB[lane];
        #pragma unroll 4
        for (int t = 0; t < M_ / 128; ++t) {
            if (t + 1 < M_ / 128) {
                na.f4 = sqA[(t + 1) * 64 + lane];
                nb.f4 = sqB[(t + 1) * 64 + lane];
            }
            v2f xs = qa.v.lo, ys = qa.v.hi, zs = qb.v.lo, ws = qb.v.hi;
            #pragma unroll
            for (int r = 0; r < RW_; ++r) {
                v2f d = v2_fma(v2_splat(rx[r]), xs,
                        v2_fma(v2_splat(ry[r]), ys,
                        v2_fma(v2_splat(rz[r]), zs, ws)));
                acc[r] = v2_min(acc[r], d);
            }
            qa = na; qb = nb;
        }
        #pragma unroll
        for (int r = 0; r < RW_; ++r)
            total += fminf(acc[r].x, acc[r].y);
        __syncthreads();   // fence: forbid LDS-load CSE across passes
    }

    // keep live: reduce within wave and write to ws (ignored by finish)
    #pragma unroll
    for (int off = 32; off; off >>= 1)
        total += __shfl_xor(total, off, 64);
    if (lane == 0) wsum[wv] = total;
    __syncthreads();
    if (tid == 0) {
        float s = 0.f;
        #pragma unroll
        for (int i = 0; i < 8; ++i) s += wsum[i];
        diag_partials[((size_t)b * 2 + dir) * GX_ + blockIdx.x] = s;
    }
}

// Finish: one block, 256 threads; reduces the 64 partials per batch.
__global__ __launch_bounds__(256) void chamfer_finish(
    const float* __restrict__ partials, float* __restrict__ loss)
{
    int t = threadIdx.x;
    int b = t >> 3, k = t & 7;
    const float4* p4 = (const float4*)(partials + b * (2 * GX_) + k * 8);
    float4 u = p4[0], v = p4[1];
    float s = ((u.x + u.y) + (u.z + u.w)) + ((v.x + v.y) + (v.z + v.w));
    #pragma unroll
    for (int off = 4; off; off >>= 1) s += __shfl_xor(s, off, 64);
    if (k == 0) loss[b] = 0.5f * s;
}

// ---------- Fallback (ws too small): prep-on-the-fly + atomics ----------
__global__ void chamfer_zero(float* __restrict__ loss)
{
    if (threadIdx.x < B_) loss[threadIdx.x] = 0.0f;
}

__global__ __launch_bounds__(256) void chamfer_nolds(
    const int* __restrict__ o_w, const float* __restrict__ o_pts,
    const int* __restrict__ t_w, const float* __restrict__ t_pts,
    float* __restrict__ loss)
{
    const int dir  = blockIdx.z;
    const int b    = blockIdx.y;
    const int lane = threadIdx.x & 63;
    const int wv   = threadIdx.x >> 6;
    const int row0 = (blockIdx.x * 4 + wv) * 16;

    const int*   __restrict__ wa = (dir == 0) ? o_w   : t_w;
    const float* __restrict__ pa = (dir == 0) ? o_pts : t_pts;
    const int*   __restrict__ wb = (dir == 0) ? t_w   : o_w;
    const float* __restrict__ pb = (dir == 0) ? t_pts : o_pts;

    int base = __builtin_amdgcn_readfirstlane((b * N_ + row0) * 3);
    const float* rp = pa + base;
    float rx[16], ry[16], rz[16];
    #pragma unroll
    for (int r = 0; r < 16; ++r) {
        rx[r] = rp[3 * r + 0];
        ry[r] = rp[3 * r + 1];
        rz[r] = rp[3 * r + 2];
    }
    float acc[16];
    #pragma unroll
    for (int r = 0; r < 16; ++r) acc[r] = 3.4e38f;

    #pragma unroll 2
    for (int t = 0; t < M_ / 64; ++t) {
        int ib = b * M_ + t * 64 + lane;
        float bx = pb[ib * 3 + 0], by = pb[ib * 3 + 1], bz = pb[ib * 3 + 2];
        float n2 = fmaf(bx, bx, fmaf(by, by, bz * bz));
        float qw = (wb[ib] != 0) ? n2 : BIG2;
        float qx = -2.0f * bx, qy = -2.0f * by, qz = -2.0f * bz;
        #pragma unroll
        for (int r = 0; r < 16; ++r) {
            float d = fmaf(rx[r], qx, fmaf(ry[r], qy, fmaf(rz[r], qz, qw)));
            acc[r] = fminf(acc[r], d);
        }
    }
    #pragma unroll
    for (int r = 0; r < 16; ++r) {
        float v = acc[r];
        #pragma unroll
        for (int off = 32; off; off >>= 1) v = fminf(v, __shfl_xor(v, off, 64));
        acc[r] = v;
    }
    int mbase = __builtin_amdgcn_readfirstlane(b * N_ + row0);
    const int* wp = wa + mbase;
    float sum = 0.0f;
    #pragma unroll
    for (int r = 0; r < 16; ++r) {
        float a2 = fmaf(rx[r], rx[r], fmaf(ry[r], ry[r], rz[r] * rz[r]));
        float d2 = fmaxf(a2 + acc[r], 0.0f);
        sum += (wp[r] != 0) ? d2 : 0.0f;
    }
    if (lane == 0) atomicAdd(&loss[b], 0.5f * sum);
}

extern "C" void kernel_launch(void* const* d_in, const int* in_sizes, int n_in,
                              void* d_out, int out_size, void* d_ws, size_t ws_size,
                              hipStream_t stream) {
    const int*   o_w   = (const int*)  d_in[0];
    const float* o_pts = (const float*)d_in[1];
    const int*   t_w   = (const int*)  d_in[2];
    const float* t_pts = (const float*)d_in[3];
    float* loss = (float*)d_out;

    const size_t part_bytes = (size_t)B_ * 2 * GX_ * sizeof(float);   // 8 KB

    if (ws_size >= 2 * part_bytes) {
        float* partials      = (float*)d_ws;
        float* diag_partials = (float*)((char*)d_ws + part_bytes);
        dim3 grid(GX_, B_, 2);                                        // (32, 32, 2)
        chamfer_main<<<grid, 512, 0, stream>>>(
            o_w, o_pts, t_w, t_pts, partials);
        chamfer_finish<<<1, 256, 0, stream>>>(partials, loss);
        // Diagnostic dispatch (output ignored; d_ws only). Runs after the
        // real result is produced. Same work every call.
        chamfer_diag<<<grid, 512, 0, stream>>>(
            o_w, o_pts, t_w, t_pts, diag_partials);
    } else {
        chamfer_zero<<<1, 64, 0, stream>>>(loss);
        dim3 grid(N_ / 64, B_, 2);
        chamfer_nolds<<<grid, 256, 0, stream>>>(
            o_w, o_pts, t_w, t_pts, loss);
    }
}

// Round 9
// 107.544 us; speedup vs baseline: 1.5070x; 1.5070x over previous
//
#include <hip/hip_runtime.h>
#include <hip/hip_bf16.h>

// Chamfer loss: B=32, N=M=2048, D=3.
// loss[b] = 0.5 * ( sum_n ma[n]*min_m d2(a_n,b_m) + sum_m mb[m]*min_n d2(b_m,a_n) )
// masked pairs -> BIG^2 = 1e16 (exact in fp32: a2 < ulp(1e16)).
//
// R9: R8's v_pk_fma_f32 failed only on the SGPR src (VOP3P needs 64-bit
// operands; the all-VGPR forms v[18:19] etc assembled fine). Fix: row coords
// pre-splat into loop-invariant v2f VGPR pairs; inner loop = 3 all-VGPR
// v_pk_fma_f32 + v_min3_f32 per (row x 2 points) -> 2 insts/point-row,
// half of R7's measured scalarized rate (VALUBusy was 81% -> issue-bound).
// Structure = R5 (verified): LDS pair-SoA, 1-deep prefetch, block store +
// finish kernel, no atomics (R3 lesson), no min-waves cap (R4 lesson).
#define B_    32
#define N_    2048
#define M_    2048
#define RW_   8        // rows per wave
#define GX_   32       // n-chunks per (b,dir): 2048 / (8 waves * 8 rows)
#define BIG2  1.0e16f

typedef float v2f __attribute__((ext_vector_type(2)));

union F4V2 { float4 f4; struct { v2f lo, hi; } v; };

// d = a*b + c, packed 2xf32 (all operands VGPR pairs — proven to assemble)
__device__ __forceinline__ v2f pk_fma(v2f a, v2f b, v2f c) {
    v2f t;
    asm("v_pk_fma_f32 %0, %1, %2, %3"
        : "=v"(t) : "v"(a), "v"(b), "v"(c));
    return t;
}
// t = a*b + t
__device__ __forceinline__ void pk_fma_acc(v2f a, v2f b, v2f& t) {
    asm("v_pk_fma_f32 %0, %1, %2, %0"
        : "+v"(t) : "v"(a), "v"(b));
}

// ---------------- Main (R5 structure + packed inner loop) ----------------
__global__ __launch_bounds__(512) void chamfer_main(
    const int* __restrict__ o_w, const float* __restrict__ o_pts,
    const int* __restrict__ t_w, const float* __restrict__ t_pts,
    float* __restrict__ partials)
{
    const int dir  = blockIdx.z;
    const int b    = blockIdx.y;
    const int tid  = threadIdx.x;
    const int lane = tid & 63;
    const int wv   = tid >> 6;
    const int row0 = blockIdx.x * (8 * RW_) + wv * RW_;

    const int*   wa; const float* pa;   // outer (row) side
    const int*   wb; const float* pb;   // inner (streamed) side
    if (dir == 0) { wa = o_w; pa = o_pts; wb = t_w; pb = t_pts; }
    else          { wa = t_w; pa = t_pts; wb = o_w; pb = o_pts; }

    __shared__ float4 sqA[M_ / 2];      // 16 KB: {-2x0,-2x1,-2y0,-2y1} per pair
    __shared__ float4 sqB[M_ / 2];      // 16 KB: {-2z0,-2z1, w0, w1} per pair
    __shared__ float  wsum[8];

    // ---- Stage inner slice: 512 threads x 2 pair-slots, coalesced float2.
    {
        const float2* src2 = (const float2*)(pb + (size_t)b * M_ * 3);
        const int2*   wb2  = (const int2*)(wb + (size_t)b * M_);
        #pragma unroll
        for (int k = 0; k < 2; ++k) {
            int p = tid + k * 512;                     // pair index 0..1023
            float2 u0 = src2[p * 3 + 0];
            float2 u1 = src2[p * 3 + 1];
            float2 u2 = src2[p * 3 + 2];
            int2   mm = wb2[p];
            float x0 = u0.x, y0 = u0.y, z0 = u1.x;
            float x1 = u1.y, y1 = u2.x, z1 = u2.y;
            float n20 = fmaf(x0, x0, fmaf(y0, y0, z0 * z0));
            float n21 = fmaf(x1, x1, fmaf(y1, y1, z1 * z1));
            sqA[p] = make_float4(-2.f * x0, -2.f * x1, -2.f * y0, -2.f * y1);
            sqB[p] = make_float4(-2.f * z0, -2.f * z1,
                                 mm.x ? n20 : BIG2, mm.y ? n21 : BIG2);
        }
    }

    // ---- Row constants (scalar for epilogue) + v2f splats for the loop.
    int base = __builtin_amdgcn_readfirstlane((b * N_ + row0) * 3);
    const float* rp = pa + base;
    float rx[RW_], ry[RW_], rz[RW_];
    v2f  rxv[RW_], ryv[RW_], rzv[RW_];
    #pragma unroll
    for (int r = 0; r < RW_; ++r) {
        rx[r] = rp[3 * r + 0];
        ry[r] = rp[3 * r + 1];
        rz[r] = rp[3 * r + 2];
        rxv[r] = (v2f){ rx[r], rx[r] };
        ryv[r] = (v2f){ ry[r], ry[r] };
        rzv[r] = (v2f){ rz[r], rz[r] };
    }
    __syncthreads();

    float acc[RW_];
    #pragma unroll
    for (int r = 0; r < RW_; ++r) acc[r] = 3.4e38f;

    // ---- Inner loop: 16 tiles of 128 points (64 pairs across lanes),
    // 1-deep LDS prefetch. Per tile per row: 3 v_pk_fma_f32 + 1 v_min3_f32.
    F4V2 qa, qb, na, nb;
    qa.f4 = sqA[lane];
    qb.f4 = sqB[lane];
    #pragma unroll 4
    for (int t = 0; t < M_ / 128; ++t) {
        if (t + 1 < M_ / 128) {
            na.f4 = sqA[(t + 1) * 64 + lane];
            nb.f4 = sqB[(t + 1) * 64 + lane];
        }
        v2f xs = qa.v.lo, ys = qa.v.hi, zs = qb.v.lo, ws = qb.v.hi;
        #pragma unroll
        for (int r = 0; r < RW_; ++r) {
            v2f d = pk_fma(rzv[r], zs, ws);     // {rz,rz}*{z0,z1} + {w0,w1}
            pk_fma_acc(ryv[r], ys, d);
            pk_fma_acc(rxv[r], xs, d);
            acc[r] = fminf(acc[r], fminf(d.x, d.y));   // -> v_min3_f32
        }
        qa = na; qb = nb;
    }

    // ---- Cross-lane min per row, epilogue, block reduce, one store.
    int mbase = __builtin_amdgcn_readfirstlane(b * N_ + row0);
    const int* wp = wa + mbase;
    float sum = 0.0f;
    #pragma unroll
    for (int r = 0; r < RW_; ++r) {
        float m = acc[r];
        #pragma unroll
        for (int off = 32; off; off >>= 1)
            m = fminf(m, __shfl_xor(m, off, 64));
        float a2 = fmaf(rx[r], rx[r], fmaf(ry[r], ry[r], rz[r] * rz[r]));
        float d2 = fmaxf(a2 + m, 0.0f);
        sum += (wp[r] != 0) ? d2 : 0.0f;
    }
    if (lane == 0) wsum[wv] = sum;
    __syncthreads();
    if (tid == 0) {
        float s = 0.f;
        #pragma unroll
        for (int i = 0; i < 8; ++i) s += wsum[i];
        partials[((size_t)b * 2 + dir) * GX_ + blockIdx.x] = s;
    }
}

// Finish: one block, 256 threads; reduces the 64 partials per batch.
__global__ __launch_bounds__(256) void chamfer_finish(
    const float* __restrict__ partials, float* __restrict__ loss)
{
    int t = threadIdx.x;
    int b = t >> 3, k = t & 7;
    const float4* p4 = (const float4*)(partials + b * (2 * GX_) + k * 8);
    float4 u = p4[0], v = p4[1];
    float s = ((u.x + u.y) + (u.z + u.w)) + ((v.x + v.y) + (v.z + v.w));
    #pragma unroll
    for (int off = 4; off; off >>= 1) s += __shfl_xor(s, off, 64);
    if (k == 0) loss[b] = 0.5f * s;
}

// ---------- Fallback (ws too small): prep-on-the-fly + atomics ----------
__global__ void chamfer_zero(float* __restrict__ loss)
{
    if (threadIdx.x < B_) loss[threadIdx.x] = 0.0f;
}

__global__ __launch_bounds__(256) void chamfer_nolds(
    const int* __restrict__ o_w, const float* __restrict__ o_pts,
    const int* __restrict__ t_w, const float* __restrict__ t_pts,
    float* __restrict__ loss)
{
    const int dir  = blockIdx.z;
    const int b    = blockIdx.y;
    const int lane = threadIdx.x & 63;
    const int wv   = threadIdx.x >> 6;
    const int row0 = (blockIdx.x * 4 + wv) * 16;

    const int*   __restrict__ wa = (dir == 0) ? o_w   : t_w;
    const float* __restrict__ pa = (dir == 0) ? o_pts : t_pts;
    const int*   __restrict__ wb = (dir == 0) ? t_w   : o_w;
    const float* __restrict__ pb = (dir == 0) ? t_pts : o_pts;

    int base = __builtin_amdgcn_readfirstlane((b * N_ + row0) * 3);
    const float* rp = pa + base;
    float rx[16], ry[16], rz[16];
    #pragma unroll
    for (int r = 0; r < 16; ++r) {
        rx[r] = rp[3 * r + 0];
        ry[r] = rp[3 * r + 1];
        rz[r] = rp[3 * r + 2];
    }
    float acc[16];
    #pragma unroll
    for (int r = 0; r < 16; ++r) acc[r] = 3.4e38f;

    #pragma unroll 2
    for (int t = 0; t < M_ / 64; ++t) {
        int ib = b * M_ + t * 64 + lane;
        float bx = pb[ib * 3 + 0], by = pb[ib * 3 + 1], bz = pb[ib * 3 + 2];
        float n2 = fmaf(bx, bx, fmaf(by, by, bz * bz));
        float qw = (wb[ib] != 0) ? n2 : BIG2;
        float qx = -2.0f * bx, qy = -2.0f * by, qz = -2.0f * bz;
        #pragma unroll
        for (int r = 0; r < 16; ++r) {
            float d = fmaf(rx[r], qx, fmaf(ry[r], qy, fmaf(rz[r], qz, qw)));
            acc[r] = fminf(acc[r], d);
        }
    }
    #pragma unroll
    for (int r = 0; r < 16; ++r) {
        float v = acc[r];
        #pragma unroll
        for (int off = 32; off; off >>= 1) v = fminf(v, __shfl_xor(v, off, 64));
        acc[r] = v;
    }
    int mbase = __builtin_amdgcn_readfirstlane(b * N_ + row0);
    const int* wp = wa + mbase;
    float sum = 0.0f;
    #pragma unroll
    for (int r = 0; r < 16; ++r) {
        float a2 = fmaf(rx[r], rx[r], fmaf(ry[r], ry[r], rz[r] * rz[r]));
        float d2 = fmaxf(a2 + acc[r], 0.0f);
        sum += (wp[r] != 0) ? d2 : 0.0f;
    }
    if (lane == 0) atomicAdd(&loss[b], 0.5f * sum);
}

extern "C" void kernel_launch(void* const* d_in, const int* in_sizes, int n_in,
                              void* d_out, int out_size, void* d_ws, size_t ws_size,
                              hipStream_t stream) {
    const int*   o_w   = (const int*)  d_in[0];
    const float* o_pts = (const float*)d_in[1];
    const int*   t_w   = (const int*)  d_in[2];
    const float* t_pts = (const float*)d_in[3];
    float* loss = (float*)d_out;

    const size_t part_bytes = (size_t)B_ * 2 * GX_ * sizeof(float);   // 8 KB

    if (ws_size >= part_bytes) {
        float* partials = (float*)d_ws;
        dim3 grid(GX_, B_, 2);                                        // (32, 32, 2)
        chamfer_main<<<grid, 512, 0, stream>>>(
            o_w, o_pts, t_w, t_pts, partials);
        chamfer_finish<<<1, 256, 0, stream>>>(partials, loss);
    } else {
        chamfer_zero<<<1, 64, 0, stream>>>(loss);
        dim3 grid(N_ / 64, B_, 2);
        chamfer_nolds<<<grid, 256, 0, stream>>>(
            o_w, o_pts, t_w, t_pts, loss);
    }
}